// Round 12
// baseline (290.964 us; speedup 1.0000x reference)
//
#include <hip/hip_runtime.h>

// Focal multi-task loss, B=4194304 rows, C=8 classes, two tasks.
// R10 (nt loads): total 272us, kernel <77us (below harness fill kernels).
// R11 (shfl labels): REGRESSED to 289 - ds_bpermute lgkm dependency
// serialized label->compute; reverted. R12 = R10 structure, unroll 4->8
// (8 nt dwordx4 + 8 nt dword in flight; VGPR ~50, fits 8 waves/SIMD).
// Fixed harness overhead (~190us fills+restore) dominates the remaining gap.

typedef float v4f __attribute__((ext_vector_type(4)));

#define B_ROWS 4194304
#define NB 1024           // blocks per task; 4096 waves/task, 32 chunks/wave
#define LOG2E 1.4426950408889634f
#define LN2   0.6931471805599453f

// pair-exchange lane l <-> l^1 via DPP quad_perm [1,0,3,2] (pure VALU)
__device__ __forceinline__ float xor1f(float x) {
    int yi = __builtin_amdgcn_update_dpp(0, __builtin_bit_cast(int, x),
                                         0xB1 /*quad_perm(1,0,3,2)*/, 0xF, 0xF, true);
    return __builtin_bit_cast(float, yi);
}

// Lane holds classes [cls_base, cls_base+4) of its row; partner has the rest.
// All pair-combines commutative -> bit-identical result in both lanes.
__device__ __forceinline__ float half_row_loss(const v4f q, const int lab,
                                               const int cls_base) {
    const float m4 = fmaxf(fmaxf(q.x, q.y), fmaxf(q.z, q.w));
    const float m  = fmaxf(m4, xor1f(m4));                 // row max over 8
    const float mL = m * LOG2E;
    const float e0 = __builtin_amdgcn_exp2f(__builtin_fmaf(q.x, LOG2E, -mL));
    const float e1 = __builtin_amdgcn_exp2f(__builtin_fmaf(q.y, LOG2E, -mL));
    const float e2 = __builtin_amdgcn_exp2f(__builtin_fmaf(q.z, LOG2E, -mL));
    const float e3 = __builtin_amdgcn_exp2f(__builtin_fmaf(q.w, LOG2E, -mL));
    const float s4 = (e0 + e1) + (e2 + e3);
    const float s  = s4 + xor1f(s4);                       // row denom over 8
    float el4 = 0.0f;                                      // e[lab] if mine else 0
    el4 = (lab == cls_base + 0) ? e0 : el4;
    el4 = (lab == cls_base + 1) ? e1 : el4;
    el4 = (lab == cls_base + 2) ? e2 : el4;
    el4 = (lab == cls_base + 3) ? e3 : el4;
    const float el = el4 + xor1f(el4);                     // e[lab]
    const float pt = el * __builtin_amdgcn_rcpf(s);
    float c = (lab == 0) ? (0.75f * LN2) : (0.25f * LN2);  // alpha_t*boost*ln2
    c = (lab == 1) ? (0.375f * LN2) : c;
    const float omp = 1.0f - pt;
    const float w = omp * omp;                             // (1-pt)^2
    const float lg = __builtin_amdgcn_logf(pt + 1e-8f);    // log2(pt+1e-8)
    return -(c * w) * lg;
}

__global__ __launch_bounds__(256, 8) void focal_partial_kernel(
    const float* __restrict__ logits_dir, const int* __restrict__ labels_dir,
    const float* __restrict__ logits_vol, const int* __restrict__ labels_vol,
    float* __restrict__ partials /* [2][NB] */)
{
    const int task = blockIdx.y;
    const float* __restrict__ logits = task ? logits_vol : logits_dir;
    const int*   __restrict__ labels = task ? labels_vol : labels_dir;

    const int tid = threadIdx.x;
    const int gid = blockIdx.x * 256 + tid;
    const int W = gid >> 6;                 // global wave id, 0..4095 per task
    const int l = tid & 63;
    const int cls_base = (l & 1) * 4;
    // wave W owns 32 consecutive 1KB chunks (32 rows each): 32KB contiguous.
    // Lane l reads the float4 at chunk-offset l*16B -> fully dense wave access.
    const v4f* __restrict__ logbase = (const v4f*)logits + (size_t)W * 2048 + l;
    // per-chunk label: lanes 2r,2r+1 read labels[...+r] -> 128B span per wave
    const int* __restrict__ labbase = labels + (size_t)W * 1024 + (l >> 1);

    float acc = 0.0f;
    #pragma unroll 8
    for (int j = 0; j < 32; ++j) {
        // NON-TEMPORAL: no L2/L3 allocation -> no dirty-line evictions
        const v4f q   = __builtin_nontemporal_load(logbase + j * 64);
        const int lab = __builtin_nontemporal_load(labbase + j * 32);
        acc += half_row_loss(q, lab, cls_base);
    }

    // wave reduce (each row counted twice -> finisher divides by 2B)
    #pragma unroll
    for (int off = 32; off > 0; off >>= 1)
        acc += __shfl_down(acc, off);

    __shared__ float lds[4];
    const int lane = threadIdx.x & 63;
    const int wid  = threadIdx.x >> 6;
    if (lane == 0) lds[wid] = acc;
    __syncthreads();
    if (threadIdx.x == 0) {
        const float bsum = (lds[0] + lds[1]) + (lds[2] + lds[3]);
        partials[task * NB + blockIdx.x] = bsum;
    }
}

__global__ __launch_bounds__(256) void focal_final_kernel(
    const float* __restrict__ partials, float* __restrict__ out)
{
    double sd = 0.0, sv = 0.0;
    for (int k = threadIdx.x; k < NB; k += 256) {
        sd += (double)partials[k];
        sv += (double)partials[NB + k];
    }
    #pragma unroll
    for (int off = 32; off > 0; off >>= 1) {
        sd += __shfl_down(sd, off);
        sv += __shfl_down(sv, off);
    }
    __shared__ double lds[8];
    const int lane = threadIdx.x & 63;
    const int wid  = threadIdx.x >> 6;
    if (lane == 0) { lds[wid] = sd; lds[4 + wid] = sv; }
    __syncthreads();
    if (threadIdx.x == 0) {
        // each row accumulated by BOTH lanes of its pair -> divide by 2B
        const double l_dir = ((lds[0] + lds[1]) + (lds[2] + lds[3])) / (2.0 * (double)B_ROWS);
        const double l_vol = ((lds[4] + lds[5]) + (lds[6] + lds[7])) / (2.0 * (double)B_ROWS);
        out[0] = (float)(l_dir + 0.5 * l_vol);  // total = 1.0*dir + 0.5*vol
        out[1] = (float)l_dir;
        out[2] = (float)l_vol;
    }
}

extern "C" void kernel_launch(void* const* d_in, const int* in_sizes, int n_in,
                              void* d_out, int out_size, void* d_ws, size_t ws_size,
                              hipStream_t stream) {
    const float* logits_dir = (const float*)d_in[0];
    const int*   labels_dir = (const int*)d_in[1];
    const float* logits_vol = (const float*)d_in[2];
    const int*   labels_vol = (const int*)d_in[3];
    float* out = (float*)d_out;
    float* partials = (float*)d_ws;  // 2*NB floats = 8 KB, fully overwritten each call

    dim3 grid(NB, 2);
    focal_partial_kernel<<<grid, 256, 0, stream>>>(logits_dir, labels_dir,
                                                   logits_vol, labels_vol, partials);
    focal_final_kernel<<<1, 256, 0, stream>>>(partials, out);
}

// Round 13
// 271.678 us; speedup vs baseline: 1.0710x; 1.0710x over previous
//
#include <hip/hip_runtime.h>

// Focal multi-task loss, B=4194304 rows, C=8 classes, two tasks.
// FINAL (= R10, best measured: total 272.1us, kernel <77us / below the
// harness's 512MB fill kernels which run at 6.8 TB/s).
// Evidence chain: R7 control (naive dense read-sum == tuned kernel == 115us)
// + WRITE_SIZE=68MB on read-only kernel -> L3 allocate-on-read thrash vs
// harness-dirtied lines; R10 nt loads fixed it (-24us total). R11 (shfl
// labels) and R12 (unroll 8) both regressed ~+18us -> R10 load shape is
// the optimum: per row one nt dwordx4 (dense 1KB/wave) + one nt dword,
// unroll 4, no cross-lane traffic in the hot loop.

typedef float v4f __attribute__((ext_vector_type(4)));

#define B_ROWS 4194304
#define NB 1024           // blocks per task; 4096 waves/task, 32 chunks/wave
#define LOG2E 1.4426950408889634f
#define LN2   0.6931471805599453f

// pair-exchange lane l <-> l^1 via DPP quad_perm [1,0,3,2] (pure VALU)
__device__ __forceinline__ float xor1f(float x) {
    int yi = __builtin_amdgcn_update_dpp(0, __builtin_bit_cast(int, x),
                                         0xB1 /*quad_perm(1,0,3,2)*/, 0xF, 0xF, true);
    return __builtin_bit_cast(float, yi);
}

// Lane holds classes [cls_base, cls_base+4) of its row; partner has the rest.
// All pair-combines commutative -> bit-identical result in both lanes.
__device__ __forceinline__ float half_row_loss(const v4f q, const int lab,
                                               const int cls_base) {
    const float m4 = fmaxf(fmaxf(q.x, q.y), fmaxf(q.z, q.w));
    const float m  = fmaxf(m4, xor1f(m4));                 // row max over 8
    const float mL = m * LOG2E;
    const float e0 = __builtin_amdgcn_exp2f(__builtin_fmaf(q.x, LOG2E, -mL));
    const float e1 = __builtin_amdgcn_exp2f(__builtin_fmaf(q.y, LOG2E, -mL));
    const float e2 = __builtin_amdgcn_exp2f(__builtin_fmaf(q.z, LOG2E, -mL));
    const float e3 = __builtin_amdgcn_exp2f(__builtin_fmaf(q.w, LOG2E, -mL));
    const float s4 = (e0 + e1) + (e2 + e3);
    const float s  = s4 + xor1f(s4);                       // row denom over 8
    float el4 = 0.0f;                                      // e[lab] if mine else 0
    el4 = (lab == cls_base + 0) ? e0 : el4;
    el4 = (lab == cls_base + 1) ? e1 : el4;
    el4 = (lab == cls_base + 2) ? e2 : el4;
    el4 = (lab == cls_base + 3) ? e3 : el4;
    const float el = el4 + xor1f(el4);                     // e[lab]
    const float pt = el * __builtin_amdgcn_rcpf(s);
    float c = (lab == 0) ? (0.75f * LN2) : (0.25f * LN2);  // alpha_t*boost*ln2
    c = (lab == 1) ? (0.375f * LN2) : c;
    const float omp = 1.0f - pt;
    const float w = omp * omp;                             // (1-pt)^2
    const float lg = __builtin_amdgcn_logf(pt + 1e-8f);    // log2(pt+1e-8)
    return -(c * w) * lg;
}

__global__ __launch_bounds__(256, 8) void focal_partial_kernel(
    const float* __restrict__ logits_dir, const int* __restrict__ labels_dir,
    const float* __restrict__ logits_vol, const int* __restrict__ labels_vol,
    float* __restrict__ partials /* [2][NB] */)
{
    const int task = blockIdx.y;
    const float* __restrict__ logits = task ? logits_vol : logits_dir;
    const int*   __restrict__ labels = task ? labels_vol : labels_dir;

    const int tid = threadIdx.x;
    const int gid = blockIdx.x * 256 + tid;
    const int W = gid >> 6;                 // global wave id, 0..4095 per task
    const int l = tid & 63;
    const int cls_base = (l & 1) * 4;
    // wave W owns 32 consecutive 1KB chunks (32 rows each): 32KB contiguous.
    // Lane l reads the float4 at chunk-offset l*16B -> fully dense wave access.
    const v4f* __restrict__ logbase = (const v4f*)logits + (size_t)W * 2048 + l;
    // per-chunk label: lanes 2r,2r+1 read labels[...+r] -> 128B span per wave
    const int* __restrict__ labbase = labels + (size_t)W * 1024 + (l >> 1);

    float acc = 0.0f;
    #pragma unroll 4
    for (int j = 0; j < 32; ++j) {
        // NON-TEMPORAL: no L2/L3 allocation -> no dirty-line evictions
        const v4f q   = __builtin_nontemporal_load(logbase + j * 64);
        const int lab = __builtin_nontemporal_load(labbase + j * 32);
        acc += half_row_loss(q, lab, cls_base);
    }

    // wave reduce (each row counted twice -> finisher divides by 2B)
    #pragma unroll
    for (int off = 32; off > 0; off >>= 1)
        acc += __shfl_down(acc, off);

    __shared__ float lds[4];
    const int lane = threadIdx.x & 63;
    const int wid  = threadIdx.x >> 6;
    if (lane == 0) lds[wid] = acc;
    __syncthreads();
    if (threadIdx.x == 0) {
        const float bsum = (lds[0] + lds[1]) + (lds[2] + lds[3]);
        partials[task * NB + blockIdx.x] = bsum;
    }
}

__global__ __launch_bounds__(256) void focal_final_kernel(
    const float* __restrict__ partials, float* __restrict__ out)
{
    double sd = 0.0, sv = 0.0;
    for (int k = threadIdx.x; k < NB; k += 256) {
        sd += (double)partials[k];
        sv += (double)partials[NB + k];
    }
    #pragma unroll
    for (int off = 32; off > 0; off >>= 1) {
        sd += __shfl_down(sd, off);
        sv += __shfl_down(sv, off);
    }
    __shared__ double lds[8];
    const int lane = threadIdx.x & 63;
    const int wid  = threadIdx.x >> 6;
    if (lane == 0) { lds[wid] = sd; lds[4 + wid] = sv; }
    __syncthreads();
    if (threadIdx.x == 0) {
        // each row accumulated by BOTH lanes of its pair -> divide by 2B
        const double l_dir = ((lds[0] + lds[1]) + (lds[2] + lds[3])) / (2.0 * (double)B_ROWS);
        const double l_vol = ((lds[4] + lds[5]) + (lds[6] + lds[7])) / (2.0 * (double)B_ROWS);
        out[0] = (float)(l_dir + 0.5 * l_vol);  // total = 1.0*dir + 0.5*vol
        out[1] = (float)l_dir;
        out[2] = (float)l_vol;
    }
}

extern "C" void kernel_launch(void* const* d_in, const int* in_sizes, int n_in,
                              void* d_out, int out_size, void* d_ws, size_t ws_size,
                              hipStream_t stream) {
    const float* logits_dir = (const float*)d_in[0];
    const int*   labels_dir = (const int*)d_in[1];
    const float* logits_vol = (const float*)d_in[2];
    const int*   labels_vol = (const int*)d_in[3];
    float* out = (float*)d_out;
    float* partials = (float*)d_ws;  // 2*NB floats = 8 KB, fully overwritten each call

    dim3 grid(NB, 2);
    focal_partial_kernel<<<grid, 256, 0, stream>>>(logits_dir, labels_dir,
                                                   logits_vol, labels_vol, partials);
    focal_final_kernel<<<1, 256, 0, stream>>>(partials, out);
}